// Round 6
// baseline (11814.507 us; speedup 1.0000x reference)
//
#include <hip/hip_runtime.h>
#include <math.h>

// ---------------------------------------------------------------------------
// StateSpaceModel: B=512 T=256 Z=128 X=64 R=1024 HT=HO=1024.
// R6: the recurrence is ROW-SEPARABLE in B -> no grid barrier needed.
// R5 profiled at 40.8us/step with MfmaUtil 6.3%: ~30us/step was the 512-block
// tree barrier (64 serialized RMWs/leaf + 512 spinners on one gen address).
// Now:
//  - 16 independent cohorts of 32 blocks; cohort g owns rows [32g,32g+32).
//    All buffers (hb16/zb16/Hbuf/GP/out rows) are cohort-private.
//  - per-cohort sync: block j stores flag[j]=ordinal (distinct u16, one 64B
//    line, no RMW); wave0 lanes 0..31 poll all 32 slots with one coalesced
//    load, compare >= (monotonic; skew<=1 phase is safe for every buffer).
//  - P3/P4 tile->block maps made cohort-local, SAME tile shapes and K-order
//    as R5 -> identical numerics.
//  - co-resident blocks on a CU are from different cohorts -> spin of one
//    overlaps compute of the other.
//  - reg-prefetch pipeline, relaxed agent-scope coherent access, bf16 weight
//    cache, h-in-registers: unchanged from R5.
// ---------------------------------------------------------------------------

typedef unsigned short u16;
typedef unsigned long long u64;
typedef __bf16 bf16x8 __attribute__((ext_vector_type(8)));
typedef u16    u16x8  __attribute__((ext_vector_type(8)));
typedef float  f32x4  __attribute__((ext_vector_type(4)));

#define DI __device__ __forceinline__
#define LDS_STRIDE 72   // 64 + 8 pad: 16B-aligned, 2-way bank alias (free)

DI u16  f2b(float f){ union{float f; unsigned u;} c; c.f = f;
                      return (u16)((c.u + 0x7fffu + ((c.u>>16)&1u))>>16); }  // RNE
DI float b2f(u16 x){ union{unsigned u; float f;} c; c.u = ((unsigned)x)<<16; return c.f; }
DI float sigm (float x){ return 1.f/(1.f+expf(-x)); }
DI float softp(float x){ return (x>15.f)? x : log1pf(expf(x)); }

DI f32x4 mfma16(bf16x8 a, bf16x8 b, f32x4 c){
  return __builtin_amdgcn_mfma_f32_16x16x32_bf16(a,b,c,0,0,0);
}
DI bf16x8 ldw8b(const u16* __restrict__ g){
  return __builtin_bit_cast(bf16x8, *(const u16x8*)g);
}
DI bf16x8 ldfragS(const u16* l, int row, int ko, int stride){
  return __builtin_bit_cast(bf16x8, *(const u16x8*)(l + row*stride + ko));
}
DI bf16x8 ldfrag(const u16* l, int row, int ko){ return ldfragS(l, row, ko, LDS_STRIDE); }

// ---- coherent (agent-scope, relaxed) access helpers: no fences -------------
DI u64 ldc64(const void* p){
  return __hip_atomic_load((const u64*)p, __ATOMIC_RELAXED, __HIP_MEMORY_SCOPE_AGENT);
}
DI u16x8 ldc128(const u16* g){
  union{u64 q[2]; u16x8 v;} u; u.q[0] = ldc64(g); u.q[1] = ldc64(g + 4); return u.v;
}
DI u16 ldc16(const u16* p){
  return __hip_atomic_load(p, __ATOMIC_RELAXED, __HIP_MEMORY_SCOPE_AGENT);
}
DI void stc16(u16* p, u16 v){
  __hip_atomic_store(p, v, __ATOMIC_RELAXED, __HIP_MEMORY_SCOPE_AGENT);
}
DI float ldc32f(const float* p){
  unsigned u = __hip_atomic_load((const unsigned*)p, __ATOMIC_RELAXED, __HIP_MEMORY_SCOPE_AGENT);
  union{unsigned u; float f;} c; c.u = u; return c.f;
}
DI void stc32f(float* p, float v){
  union{float f; unsigned u;} c; c.f = v;
  __hip_atomic_store((unsigned*)p, c.u, __ATOMIC_RELAXED, __HIP_MEMORY_SCOPE_AGENT);
}

// ---- per-cohort sync: 32 blocks, one 64B flag line, monotonic ordinals -----
// Producer data stores are drained by __syncthreads (vmcnt 0 per wave before
// barrier), so the flag store is causally after them. Consumers use relaxed
// agent-scope loads (bypass stale L1/L2) for data -> same discipline that
// passed in R4/R5.
DI void csync(u16* cf, unsigned s, int lblk){
  __syncthreads();
  if(threadIdx.x == 0)
    __hip_atomic_store(cf + lblk, (u16)s, __ATOMIC_RELAXED, __HIP_MEMORY_SCOPE_AGENT);
  if(threadIdx.x < 32){
    while((unsigned)__hip_atomic_load(cf + threadIdx.x, __ATOMIC_RELAXED,
                                      __HIP_MEMORY_SCOPE_AGENT) < s)
      __builtin_amdgcn_s_sleep(1);
  }
  asm volatile("" ::: "memory");
  __syncthreads();
}

// ---------------- one-time fp32 -> bf16 weight conversion -------------------
__global__ __launch_bounds__(256) void k_cvt(const float* __restrict__ s,
                                             u16* __restrict__ d){
  int i = (blockIdx.x*256 + threadIdx.x)*8;
  f32x4 p0 = *(const f32x4*)(s+i), p1 = *(const f32x4*)(s+i+4);
  u16x8 o;
  o[0]=f2b(p0[0]); o[1]=f2b(p0[1]); o[2]=f2b(p0[2]); o[3]=f2b(p0[3]);
  o[4]=f2b(p1[0]); o[5]=f2b(p1[1]); o[6]=f2b(p1[2]); o[7]=f2b(p1[3]);
  *(u16x8*)(d+i) = o;
}

__global__ __launch_bounds__(256) void k_init(u16* __restrict__ hb,
                                              u16* __restrict__ zb,
                                              const float* __restrict__ h0,
                                              const float* __restrict__ z0){
  int idx = blockIdx.x*256 + threadIdx.x;           // 2048 blocks -> 524288
  hb[idx] = f2b(h0[idx & 1023]);
  if(idx < 512*128) zb[idx] = f2b(z0[idx & 127]);
}

__global__ void k_bzero(unsigned* b){ b[threadIdx.x] = 0u; b[threadIdx.x+256] = 0u; }

// ------------------------- persistent sequential kernel ---------------------
struct SeqP {
  const float *eps, *h0, *z0;
  const float *gbih, *gbhh, *tgb, *tpb, *tlb, *tghzb, *tphzb, *tsb;
  const u16 *wih, *whh, *tgw, *tpw, *tlw, *tghzw, *tphzw, *tsw;
  float *out, *GP;
  u16 *Hbuf, *hb16, *zb16;
  u16 *flags;                        // 16 cohorts x 64 u16 (128B stride)
};

// 32m x 64n x K=1024 tile: C = act(A @ W^T + b); depth-4 reg prefetch,
// raw s_barrier (1/iter), LDS dbuf 2x6912 u16.
DI void mlp_tile(const u16* __restrict__ A,      // + m0*1024 applied by caller
                 const u16* __restrict__ W,      // 64 region rows x 1024
                 const float* __restrict__ bias, int act,
                 u16* __restrict__ Cb,           // Hbuf + m0*2176 + n0
                 u16* smem, int tid)
{
  const int lane=tid&63, w=tid>>6, l16=lane&15, quad=lane>>4, wm=w>>1, wn=w&1;
  const int ar=tid>>3, ac=(tid&7)*8, br=tid>>2, bc=(tid&3)*16;
  f32x4 acc[2] = {};
  u16x8 a0,a1,a2,a3,u0,u1,u2,u3,v0,v1,v2,v3;
#define MT_ISSUE(ra,ru,rv,is) do{ \
    ra = ldc128(A + (size_t)ar*1024 + (is)*64 + ac); \
    ru = *(const u16x8*)(W + (size_t)br*1024 + (is)*64 + bc); \
    rv = *(const u16x8*)(W + (size_t)br*1024 + (is)*64 + bc + 8); \
  }while(0)
#define MT_STEP(ra,ru,rv,it,nx) do{ \
    u16* b_ = smem + ((it)&1)*6912; \
    *(u16x8*)(b_ + ar*LDS_STRIDE + ac) = ra; \
    *(u16x8*)(b_ + 2304 + br*LDS_STRIDE + bc) = ru; \
    *(u16x8*)(b_ + 2304 + br*LDS_STRIDE + bc + 8) = rv; \
    asm volatile("s_waitcnt lgkmcnt(0)" ::: "memory"); \
    __builtin_amdgcn_s_barrier(); \
    __builtin_amdgcn_sched_barrier(0); \
    if((nx) < 16) MT_ISSUE(ra,ru,rv,(nx)); \
    _Pragma("unroll") \
    for(int kc=0;kc<2;kc++){ \
      int ko = kc*32 + quad*8; \
      bf16x8 aa = ldfrag(b_, wm*16 + l16, ko); \
      bf16x8 q0 = ldfrag(b_ + 2304, wn*32 + l16, ko); \
      bf16x8 q1 = ldfrag(b_ + 2304, wn*32 + 16 + l16, ko); \
      acc[0] = mfma16(aa,q0,acc[0]); \
      acc[1] = mfma16(aa,q1,acc[1]); \
    } \
  }while(0)
  MT_ISSUE(a0,u0,v0,0); MT_ISSUE(a1,u1,v1,1);
  MT_ISSUE(a2,u2,v2,2); MT_ISSUE(a3,u3,v3,3);
#pragma unroll 1
  for(int ib=0; ib<16; ib+=4){
    MT_STEP(a0,u0,v0, ib+0, ib+4);
    MT_STEP(a1,u1,v1, ib+1, ib+5);
    MT_STEP(a2,u2,v2, ib+2, ib+6);
    MT_STEP(a3,u3,v3, ib+3, ib+7);
  }
#undef MT_ISSUE
#undef MT_STEP
  __syncthreads();
#pragma unroll
  for(int nf=0; nf<2; nf++)
#pragma unroll
  for(int i=0; i<4; i++){
    int m  = wm*16 + quad*4 + i;
    int cl = wn*32 + nf*16 + l16;
    float v = acc[nf][i] + bias[cl];
    if(act) v = fmaxf(v, 0.f);
    stc16(&Cb[(size_t)m*2176 + cl], f2b(v));
  }
}

__global__ __launch_bounds__(256, 2) void k_seq(SeqP p)
{
  __shared__ u16 smem[18432];                   // 36.9 KB (2 dbuf x 9216)
  const int blk  = blockIdx.x;                  // 0..511
  const int tid  = threadIdx.x;
  const int g    = blk >> 5;                    // cohort 0..15 (rows 32g..+32)
  const int lblk = blk & 31;                    // block-in-cohort
  u16* cf = p.flags + g*64;                     // cohort flag line (128B)
  const int lane = tid & 63, w = tid >> 6;
  const int l16  = lane & 15, quad = lane >> 4;
  const int wm   = w >> 1, wn = w & 1;
  const int ar   = tid >> 3, ac = (tid & 7) * 8;   // 32-row tile staging

  // P1 fixed tile mapping (same every step) -> h lives in registers
  const int p1m0 = g * 32;
  const int p1n0 = lblk * 32;
  const int p1n  = p1n0 + wn*16 + l16;
  f32x4 hreg;
  { float h0v = p.h0[p1n]; hreg[0]=h0v; hreg[1]=h0v; hreg[2]=h0v; hreg[3]=h0v; }

  unsigned s = 0;                               // sync ordinal (monotonic)

#pragma unroll 1
  for(int t = 0; t < 256; t++){
    const u16* hbi = p.hb16 + (size_t)(t&1)*524288;
    u16*       hbo = p.hb16 + (size_t)((t+1)&1)*524288;

    // ========== P1: GRU, 32 tiles 32m x 32n x 3 gates, 18 iters, depth 3 ===
    {
      f32x4 acc[4] = {};              // 0=r, 1=z, 2=i_n, 3=h_n
      u16x8 a0,a1,a2, w00,w01,w02, w10,w11,w12, w20,w21,w22;
#define P1_ISSUE(ra,r0,r1,r2,is) do{ \
      const u16 *A_, *W_; int ld_, k0_; \
      if((is) < 2){ A_ = p.zb16 + (size_t)p1m0*128;  W_ = p.wih; ld_=128;  k0_=(is)*64; } \
      else        { A_ = hbi    + (size_t)p1m0*1024; W_ = p.whh; ld_=1024; k0_=((is)-2)*64; } \
      ra = ldc128(A_ + (size_t)ar*ld_ + k0_ + ac); \
      r0 = *(const u16x8*)(W_ + (size_t)(p1n0 + ar)*ld_        + k0_ + ac); \
      r1 = *(const u16x8*)(W_ + (size_t)(1024 + p1n0 + ar)*ld_ + k0_ + ac); \
      r2 = *(const u16x8*)(W_ + (size_t)(2048 + p1n0 + ar)*ld_ + k0_ + ac); \
    }while(0)
#define P1_STEP(ra,r0,r1,r2,it,nx) do{ \
      u16* b_ = smem + ((it)&1)*9216; \
      *(u16x8*)(b_ + ar*LDS_STRIDE + ac) = ra; \
      *(u16x8*)(b_ + 2304 + ar*LDS_STRIDE + ac) = r0; \
      *(u16x8*)(b_ + 4608 + ar*LDS_STRIDE + ac) = r1; \
      *(u16x8*)(b_ + 6912 + ar*LDS_STRIDE + ac) = r2; \
      asm volatile("s_waitcnt lgkmcnt(0)" ::: "memory"); \
      __builtin_amdgcn_s_barrier(); \
      __builtin_amdgcn_sched_barrier(0); \
      if((nx) < 18) P1_ISSUE(ra,r0,r1,r2,(nx)); \
      const int ai3_ = ((it) < 2) ? 2 : 3; \
      _Pragma("unroll") \
      for(int kc=0;kc<2;kc++){ \
        int ko = kc*32 + quad*8; \
        bf16x8 aa  = ldfrag(b_, wm*16 + l16, ko); \
        bf16x8 b0v = ldfrag(b_ + 2304, wn*16 + l16, ko); \
        bf16x8 b1v = ldfrag(b_ + 4608, wn*16 + l16, ko); \
        bf16x8 b2v = ldfrag(b_ + 6912, wn*16 + l16, ko); \
        acc[0]    = mfma16(aa,b0v,acc[0]); \
        acc[1]    = mfma16(aa,b1v,acc[1]); \
        acc[ai3_] = mfma16(aa,b2v,acc[ai3_]); \
      } \
    }while(0)
      P1_ISSUE(a0,w00,w01,w02,0);
      P1_ISSUE(a1,w10,w11,w12,1);
      P1_ISSUE(a2,w20,w21,w22,2);
#pragma unroll 1
      for(int ib=0; ib<18; ib+=3){
        P1_STEP(a0,w00,w01,w02, ib+0, ib+3);
        P1_STEP(a1,w10,w11,w12, ib+1, ib+4);
        P1_STEP(a2,w20,w21,w22, ib+2, ib+5);
      }
#undef P1_ISSUE
#undef P1_STEP
      __syncthreads();
#pragma unroll
      for(int i=0; i<4; i++){
        int m = p1m0 + wm*16 + quad*4 + i;
        int n = p1n;
        float r  = sigm (acc[0][i] + p.gbih[n]      + p.gbhh[n]);
        float z  = sigm (acc[1][i] + p.gbih[n+1024] + p.gbhh[n+1024]);
        float nn = tanhf(acc[2][i] + p.gbih[n+2048]
                         + r*(acc[3][i] + p.gbhh[n+2048]));
        float hv = (1.f-z)*nn + z*hreg[i];
        hreg[i] = hv;
        stc16(&hbo[(size_t)m*1024 + n], f2b(hv));
      }
    }
    csync(cf, ++s, lblk);

    // ========== P2: gate+prop hidden (2048 cols), 32 tiles 32m x 64n =======
    {
      const int m0 = g * 32;
      const int n0 = lblk * 64;                   // 0..1984
      const u16* W; const float* bias;
      if(n0 < 1024){ W = p.tgw + (size_t)n0*1024;        bias = p.tgb + n0; }
      else         { W = p.tpw + (size_t)(n0-1024)*1024; bias = p.tpb + (n0-1024); }
      mlp_tile(hbo + (size_t)m0*1024, W, bias, 1,
               p.Hbuf + (size_t)m0*2176 + n0, smem, tid);
    }
    csync(cf, ++s, lblk);

    // ========== P3: GP gemm (8 tiles 32x32, depth 4) + loc (2 tiles) =======
    if(lblk < 8){
      const int m0 = g * 32, n0 = lblk * 32;
      const int reg1 = (n0 >= 128);
      const u16*  A = p.Hbuf + (size_t)m0*2176 + (reg1 ? 1024 : 0);
      const u16*  W = reg1 ? p.tphzw + (size_t)(n0-128)*1024
                           : p.tghzw + (size_t)n0*1024;
      const float* bias = reg1 ? p.tphzb + (n0-128) : p.tghzb + n0;
      f32x4 acc3 = {};
      u16x8 a0,a1,a2,a3, q0,q1,q2,q3;
#define P3_ISSUE(ra,rw,is) do{ \
      ra = ldc128(A + (size_t)ar*2176 + (is)*64 + ac); \
      rw = *(const u16x8*)(W + (size_t)ar*1024 + (is)*64 + ac); \
    }while(0)
#define P3_STEP(ra,rw,it,nx) do{ \
      u16* b_ = smem + ((it)&1)*4608; \
      *(u16x8*)(b_ + ar*LDS_STRIDE + ac) = ra; \
      *(u16x8*)(b_ + 2304 + ar*LDS_STRIDE + ac) = rw; \
      asm volatile("s_waitcnt lgkmcnt(0)" ::: "memory"); \
      __builtin_amdgcn_s_barrier(); \
      __builtin_amdgcn_sched_barrier(0); \
      if((nx) < 16) P3_ISSUE(ra,rw,(nx)); \
      _Pragma("unroll") \
      for(int kc=0;kc<2;kc++){ \
        int ko = kc*32 + quad*8; \
        acc3 = mfma16(ldfrag(b_, wm*16 + l16, ko), \
                      ldfrag(b_ + 2304, wn*16 + l16, ko), acc3); \
      } \
    }while(0)
      P3_ISSUE(a0,q0,0); P3_ISSUE(a1,q1,1); P3_ISSUE(a2,q2,2); P3_ISSUE(a3,q3,3);
#pragma unroll 1
      for(int ib=0; ib<16; ib+=4){
        P3_STEP(a0,q0, ib+0, ib+4);
        P3_STEP(a1,q1, ib+1, ib+5);
        P3_STEP(a2,q2, ib+2, ib+6);
        P3_STEP(a3,q3, ib+3, ib+7);
      }
#undef P3_ISSUE
#undef P3_STEP
      __syncthreads();
#pragma unroll
      for(int i=0; i<4; i++){
        int m  = m0 + wm*16 + quad*4 + i;
        int cl = wn*16 + l16;
        stc32f(&p.GP[(size_t)m*256 + n0 + cl], acc3[i] + bias[cl]);
      }
    } else if(lblk < 10){
      const int m0  = g * 32;
      const int n0l = 2048 + (lblk - 8) * 64;
      mlp_tile(hbo + (size_t)m0*1024, p.tlw + (size_t)(n0l-2048)*1024,
               p.tlb + (n0l-2048), 0,
               p.Hbuf + (size_t)m0*2176 + n0l, smem, tid);
    }
    csync(cf, ++s, lblk);

    // ========== P4: z_t scale GEMM (K=128) + reparam, 4 tiles 16m x 64n ====
    if(lblk < 4){
      const int m0 = g*32 + (lblk >> 1)*16, n0 = (lblk & 1)*64;
      u16* lp = smem;                           // 16 x 136
      {
        int r = tid >> 4, c = (tid & 15) * 8;
        const float* src = p.GP + (size_t)(m0+r)*256 + 128 + c;
        union{u64 q; float f[2];} q0,q1,q2,q3;
        q0.q = ldc64(src);   q1.q = ldc64(src+2);
        q2.q = ldc64(src+4); q3.q = ldc64(src+6);
        u16x8 o;
        o[0]=f2b(fmaxf(q0.f[0],0.f)); o[1]=f2b(fmaxf(q0.f[1],0.f));
        o[2]=f2b(fmaxf(q1.f[0],0.f)); o[3]=f2b(fmaxf(q1.f[1],0.f));
        o[4]=f2b(fmaxf(q2.f[0],0.f)); o[5]=f2b(fmaxf(q2.f[1],0.f));
        o[6]=f2b(fmaxf(q3.f[0],0.f)); o[7]=f2b(fmaxf(q3.f[1],0.f));
        *(u16x8*)(lp + r*136 + c) = o;
      }
      __syncthreads();
      f32x4 acc4 = {};
      const int col = n0 + w*16 + l16;
#pragma unroll
      for(int kc=0; kc<4; kc++){
        int ko = kc*32 + quad*8;
        acc4 = mfma16(ldfragS(lp, l16, ko, 136),
                      ldw8b(p.tsw + (size_t)col*128 + ko), acc4);
      }
#pragma unroll
      for(int i=0; i<4; i++){
        int gm = m0 + quad*4 + i;
        float zs  = softp(acc4[i] + p.tsb[col]);
        float gt  = sigm(ldc32f(&p.GP[(size_t)gm*256 + col]));
        float pv  = ldc32f(&p.GP[(size_t)gm*256 + 128 + col]);
        float loc = b2f(ldc16(&p.Hbuf[(size_t)gm*2176 + 2048 + col]));
        float zl  = (1.f-gt)*loc + gt*pv;
        float e   = p.eps[(size_t)gm*32768 + (size_t)t*128 + col];
        float zv  = zl + zs*e;
        p.out[(size_t)gm*32768 + (size_t)t*128 + col] = zv;
        stc16(&p.zb16[(size_t)gm*128 + col], f2b(zv));
      }
    }
    csync(cf, ++s, lblk);
  }
}

// ------------------- FUSED obs branch: one block = 32 rows ------------------
// grid 4096. Reads z (fp32) from out[b,t,0:128], overwrites with x_loc|x_scale.
#define LH_S 520
__global__ __launch_bounds__(256) void k_obs(
  const u16* __restrict__ ogw,   const float* __restrict__ ogb,
  const u16* __restrict__ oghzw, const float* __restrict__ oghzb,
  const u16* __restrict__ opw,   const float* __restrict__ opb,
  const u16* __restrict__ ophzw, const float* __restrict__ ophzb,
  const u16* __restrict__ olw,   const float* __restrict__ olb,
  const u16* __restrict__ osw,   const float* __restrict__ osb,
  float* __restrict__ out)
{
  __shared__ u16 lz[32*136];
  __shared__ u16 lh[32*LH_S];
  __shared__ u16 lp[32*72];
  const int r0 = blockIdx.x*32;
  const int t  = r0 >> 9, b0 = r0 & 511;        // 32 | 512 -> single t per block
  const int tid = threadIdx.x;
  const int lane = tid & 63, w = tid>>6, l16 = lane&15, quad = lane>>4;

#pragma unroll
  for(int i=0;i<2;i++){
    int ch = tid + i*256;
    int r = ch>>4, c = (ch&15)*8;
    const float* src = out + (size_t)(b0+r)*32768 + (size_t)t*128 + c;
    f32x4 p0 = *(const f32x4*)src, p1 = *(const f32x4*)(src+4);
    u16x8 o;
    o[0]=f2b(p0[0]); o[1]=f2b(p0[1]); o[2]=f2b(p0[2]); o[3]=f2b(p0[3]);
    o[4]=f2b(p1[0]); o[5]=f2b(p1[1]); o[6]=f2b(p1[2]); o[7]=f2b(p1[3]);
    *(u16x8*)(lz + r*136 + c) = o;
  }
  __syncthreads();

  f32x4 accp[2] = {}, accg[2] = {};
  const int col = w*16 + l16;                   // this wave's output column

#pragma unroll 1
  for(int ph=0; ph<2; ph++){                    // 0 = prop path, 1 = gate path
    const u16* hw = ph ? ogw   : opw;
    const float* hb = ph ? ogb : opb;
    const u16* zw = ph ? oghzw : ophzw;
    f32x4* acc2    = ph ? accg : accp;
#pragma unroll 1
    for(int c2=0; c2<2; c2++){                  // hidden cols [c2*512, +512)
      __syncthreads();                          // protect lh from prior readers
      for(int nt = w; nt < 32; nt += 4){
        int n = c2*512 + nt*16 + l16;           // hidden unit = weight row
#pragma unroll
        for(int mi=0; mi<2; mi++){
          f32x4 a = {};
#pragma unroll
          for(int kc=0;kc<4;kc++){
            int ko = kc*32 + quad*8;
            a = mfma16(ldfragS(lz, mi*16+l16, ko, 136),
                       ldw8b(hw + (size_t)n*128 + ko), a);
          }
          float bias = hb[n];
#pragma unroll
          for(int i=0;i<4;i++)
            lh[(mi*16+quad*4+i)*LH_S + nt*16 + l16] = f2b(fmaxf(a[i]+bias, 0.f));
        }
      }
      __syncthreads();
#pragma unroll
      for(int mi=0;mi<2;mi++){
        f32x4 a = acc2[mi];
        for(int kc=0;kc<16;kc++){
          int ko = kc*32 + quad*8;
          a = mfma16(ldfragS(lh, mi*16+l16, ko, LH_S),
                     ldw8b(zw + (size_t)col*1024 + c2*512 + ko), a);
        }
        acc2[mi] = a;
      }
    }
    if(ph==0){
      float bias = ophzb[col];
#pragma unroll
      for(int mi=0;mi<2;mi++)
#pragma unroll
      for(int i=0;i<4;i++){
        float pv = accp[mi][i] + bias;          // proposed incl. bias
        accp[mi][i] = pv;
        lp[(mi*16+quad*4+i)*72 + col] = f2b(fmaxf(pv, 0.f));
      }
    }
  }

  f32x4 accl[2]={}, accs[2]={};
#pragma unroll
  for(int mi=0;mi<2;mi++){
#pragma unroll
    for(int kc=0;kc<4;kc++){
      int ko=kc*32+quad*8;
      accl[mi]=mfma16(ldfragS(lz,mi*16+l16,ko,136),
                      ldw8b(olw + (size_t)col*128 + ko), accl[mi]);
    }
#pragma unroll
    for(int kc=0;kc<2;kc++){
      int ko=kc*32+quad*8;
      accs[mi]=mfma16(ldfragS(lp,mi*16+l16,ko,72),
                      ldw8b(osw + (size_t)col*64 + ko), accs[mi]);
    }
  }
#pragma unroll
  for(int mi=0;mi<2;mi++)
#pragma unroll
  for(int i=0;i<4;i++){
    int r = mi*16 + quad*4 + i;
    float g  = sigm(accg[mi][i] + oghzb[col]);
    float pv = accp[mi][i];
    float lc = accl[mi][i] + olb[col];
    float xs = softp(accs[mi][i] + osb[col]);
    float xl = (1.f-g)*lc + g*pv;
    size_t o = (size_t)(b0+r)*32768 + (size_t)t*128 + col;
    out[o]      = xl;
    out[o + 64] = xs;
  }
}

// ---------------------------------------------------------------------------
extern "C" void kernel_launch(void* const* d_in, const int* in_sizes, int n_in,
                              void* d_out, int out_size, void* d_ws, size_t ws_size,
                              hipStream_t stream)
{
  (void)in_sizes; (void)n_in; (void)out_size; (void)ws_size;
  const float* eps   = (const float*)d_in[1];
  const float* z0    = (const float*)d_in[2];
  const float* h0    = (const float*)d_in[3];
  const float* gwih  = (const float*)d_in[4];  const float* gbih  = (const float*)d_in[5];
  const float* gwhh  = (const float*)d_in[6];  const float* gbhh  = (const float*)d_in[7];
  const float* tgw   = (const float*)d_in[8];  const float* tgb   = (const float*)d_in[9];
  const float* tghzw = (const float*)d_in[10]; const float* tghzb = (const float*)d_in[11];
  const float* tpw   = (const float*)d_in[12]; const float* tpb   = (const float*)d_in[13];
  const float* tphzw = (const float*)d_in[14]; const float* tphzb = (const float*)d_in[15];
  const float* tlw   = (const float*)d_in[16]; const float* tlb   = (const float*)d_in[17];
  const float* tsw   = (const float*)d_in[18]; const float* tsb   = (const float*)d_in[19];
  const float* ogw   = (const float*)d_in[20]; const float* ogb   = (const float*)d_in[21];
  const float* oghzw = (const float*)d_in[22]; const float* oghzb = (const float*)d_in[23];
  const float* opw   = (const float*)d_in[24]; const float* opb   = (const float*)d_in[25];
  const float* ophzw = (const float*)d_in[26]; const float* ophzb = (const float*)d_in[27];
  const float* olw   = (const float*)d_in[28]; const float* olb   = (const float*)d_in[29];
  const float* osw   = (const float*)d_in[30]; const float* osb   = (const float*)d_in[31];
  float* out = (float*)d_out;

  // ---- ws layout (~17.9 MB total) ----
  char* ws = (char*)d_ws;
  size_t off = 0;
  u16*   Hbuf = (u16*)  (ws + off); off += (size_t)512*2176*2;     // 2.23 MB
  float* GP   = (float*)(ws + off); off += (size_t)512*256*4;      // 0.52 MB
  u16*   hb16 = (u16*)  (ws + off); off += (size_t)2*512*1024*2;   // 2.10 MB
  u16*   zb16 = (u16*)  (ws + off); off += (size_t)512*128*2;      // 0.13 MB
  u16* wc_gwih  = (u16*)(ws + off); off += (size_t)3072*128 *2;
  u16* wc_gwhh  = (u16*)(ws + off); off += (size_t)3072*1024*2;
  u16* wc_tgw   = (u16*)(ws + off); off += (size_t)1024*1024*2;
  u16* wc_tpw   = (u16*)(ws + off); off += (size_t)1024*1024*2;
  u16* wc_tlw   = (u16*)(ws + off); off += (size_t)128*1024 *2;
  u16* wc_tghzw = (u16*)(ws + off); off += (size_t)128*1024 *2;
  u16* wc_tphzw = (u16*)(ws + off); off += (size_t)128*1024 *2;
  u16* wc_tsw   = (u16*)(ws + off); off += (size_t)128*128  *2;
  u16* wc_ogw   = (u16*)(ws + off); off += (size_t)1024*128 *2;
  u16* wc_opw   = (u16*)(ws + off); off += (size_t)1024*128 *2;
  u16* wc_oghzw = (u16*)(ws + off); off += (size_t)64*1024  *2;
  u16* wc_ophzw = (u16*)(ws + off); off += (size_t)64*1024  *2;
  u16* wc_olw   = (u16*)(ws + off); off += (size_t)64*128   *2;
  u16* wc_osw   = (u16*)(ws + off); off += (size_t)64*64    *2;
  unsigned* bar = (unsigned*)(ws + off); off += 2048;              // flag lines

  // ---- one-time weight conversion (per call; inputs may be re-poisoned) ----
  #define CVT(src, dst, n) k_cvt<<<(n)/2048, 256, 0, stream>>>((src), (dst))
  CVT(gwih,  wc_gwih,  3072*128);
  CVT(gwhh,  wc_gwhh,  3072*1024);
  CVT(tgw,   wc_tgw,   1024*1024);
  CVT(tpw,   wc_tpw,   1024*1024);
  CVT(tlw,   wc_tlw,   128*1024);
  CVT(tghzw, wc_tghzw, 128*1024);
  CVT(tphzw, wc_tphzw, 128*1024);
  CVT(tsw,   wc_tsw,   128*128);
  CVT(ogw,   wc_ogw,   1024*128);
  CVT(opw,   wc_opw,   1024*128);
  CVT(oghzw, wc_oghzw, 64*1024);
  CVT(ophzw, wc_ophzw, 64*1024);
  CVT(olw,   wc_olw,   64*128);
  CVT(osw,   wc_osw,   64*64);
  #undef CVT
  k_init <<<2048, 256, 0, stream>>>(hb16, zb16, h0, z0);
  k_bzero<<<1, 256, 0, stream>>>(bar);

  // ---- persistent recurrence (16 independent cohorts, flag-line syncs) ----
  SeqP sp;
  sp.eps = eps; sp.h0 = h0; sp.z0 = z0;
  sp.gbih = gbih; sp.gbhh = gbhh;
  sp.tgb = tgb; sp.tpb = tpb; sp.tlb = tlb;
  sp.tghzb = tghzb; sp.tphzb = tphzb; sp.tsb = tsb;
  sp.wih = wc_gwih; sp.whh = wc_gwhh;
  sp.tgw = wc_tgw; sp.tpw = wc_tpw; sp.tlw = wc_tlw;
  sp.tghzw = wc_tghzw; sp.tphzw = wc_tphzw; sp.tsw = wc_tsw;
  sp.out = out; sp.GP = GP;
  sp.Hbuf = Hbuf; sp.hb16 = hb16; sp.zb16 = zb16;
  sp.flags = (u16*)bar;
  k_seq<<<512, 256, 0, stream>>>(sp);

  // fused obs: reads z from out slices, overwrites them with x_loc|x_scale
  k_obs<<<4096, 256, 0, stream>>>(wc_ogw, ogb, wc_oghzw, oghzb,
                                  wc_opw, opb, wc_ophzw, ophzb,
                                  wc_olw, olb, wc_osw, osb, out);
}